// Round 11
// baseline (1014.431 us; speedup 1.0000x reference)
//
#include <hip/hip_runtime.h>

#define NN     1024
#define IN_D   256
#define OUT_D  256
#define RPB    2                   // rows per block; grid = 512 = 2 blocks/CU
#define NPAIRS (IN_D / 2)          // 128 i-pairs
#define CP     8                   // i-pairs per chunk (16 i)
#define NCHUNK (NPAIRS / CP)       // 16 chunks

typedef float v2f __attribute__((ext_vector_type(2)));
typedef float v4f __attribute__((ext_vector_type(4)));

#define WLR_BYTES   (sizeof(float4) * NPAIRS * OUT_D)   // 512 KB
#define SINK_FLOATS ((NN / RPB) * 256)                  // 131072
#define ABL_BYTES   (WLR_BYTES + 5 * SINK_FLOATS * sizeof(float))

__global__ __launch_bounds__(256) void fz_prep(
    const float* __restrict__ wb, const float* __restrict__ wa,
    const float* __restrict__ wc, float4* __restrict__ wlr2) {
    int t = blockIdx.x * 256 + threadIdx.x;
    int pr = t >> 8;
    int o  = t & (OUT_D - 1);
    int i0 = (2 * pr) * OUT_D + o;
    int i1 = i0 + OUT_D;
    float4 w;
    w.x = wb[i0] - fmaxf(wa[i0], 0.0f);
    w.y = wb[i0] + fmaxf(wc[i0], 0.0f);
    w.z = wb[i1] - fmaxf(wa[i1], 0.0f);
    w.w = wb[i1] + fmaxf(wc[i1], 0.0f);
    wlr2[t] = w;
}

__device__ __forceinline__ void fz_tri(float a, float b, float wl, float wr,
                                       float& aL, float& aR) {
    // invariants: b >= a (hr >= hl), wr > 0
    float x  = a * wl;
    float y  = b * wl;
    float zl = a * wr;
    float zr = b * wr;
    aL += fminf(fminf(x, y), zl);
    aR += fmaxf(fmaxf(x, y), zr);
}

// MODE: 0=full  1=noW(gll+w-ds removed)  2=noH(broadcast reads removed)
//       3=noVALU(math stripped)          4=noBar(chunk barriers removed)
template <int MODE, int REPS, bool WOUT>
__device__ __forceinline__ void fz_core(
    const float* __restrict__ hl, const float* __restrict__ hr,
    const float4* __restrict__ wlr2,
    const float* __restrict__ bb, const float* __restrict__ ba,
    const float* __restrict__ bc,
    float* __restrict__ out, float* __restrict__ sinkbuf) {
    __shared__ __align__(16) v4f wbuf[2][CP][OUT_D];   // 64 KB
    __shared__ __align__(16) v2f ab[RPB][IN_D];        // 4 KB

    const int tid = threadIdx.x;
    const int o   = tid;
    const int n0  = blockIdx.x * RPB;

    int jit = 0;
    if (REPS > 1) asm volatile("v_mov_b32 %0, 0" : "=v"(jit));  // opaque 0

    float oc0 = 0.0f, oc1 = 0.0f, oc2 = 0.0f, oc3 = 0.0f;
    if (MODE == 1 || MODE == 2) {
        asm volatile("v_mov_b32 %0, 0x3d23d70a" : "=v"(oc0));   // 0.04
        asm volatile("v_mov_b32 %0, 0x3d4ccccd" : "=v"(oc1));   // 0.05
        asm volatile("v_mov_b32 %0, 0x3f000000" : "=v"(oc2));   // 0.5
        asm volatile("v_mov_b32 %0, 0x3f800000" : "=v"(oc3));   // 1.0
    }

    float aL0 = 0.0f, aR0 = 0.0f, aL1 = 0.0f, aR1 = 0.0f;

#pragma unroll 1
    for (int rep = 0; rep < REPS; ++rep) {
        if (REPS > 1) __syncthreads();       // settle wbuf/ab reuse across reps
        const int off = jit * rep;           // runtime 0, defeats CSE
        // ---- stage h rows ----
        if (tid < RPB * (IN_D / 4)) {
            int row = tid >> 6, c4 = tid & 63;
            v4f A = *reinterpret_cast<const v4f*>(&hl[(n0 + row) * IN_D + c4 * 4 + off]);
            v4f B = *reinterpret_cast<const v4f*>(&hr[(n0 + row) * IN_D + c4 * 4 + off]);
            v2f* dst = &ab[row][c4 * 4];
            v2f t0; t0.x = A.x; t0.y = B.x; dst[0] = t0;
            v2f t1; t1.x = A.y; t1.y = B.y; dst[1] = t1;
            v2f t2; t2.x = A.z; t2.y = B.z; dst[2] = t2;
            v2f t3; t3.x = A.w; t3.y = B.w; dst[3] = t3;
        }
        const float4* wbase = wlr2 + off;
        if (MODE != 1) {
#pragma unroll
            for (int p = 0; p < CP; ++p) {
                const float4* g = &wbase[(size_t)p * OUT_D + o];
                __builtin_amdgcn_global_load_lds(
                    (const __attribute__((address_space(1))) void*)g,
                    (__attribute__((address_space(3))) void*)&wbuf[0][p][o], 16, 0, 0);
            }
        }
        __syncthreads();

#pragma unroll 1
        for (int c = 0; c < NCHUNK; ++c) {
            if (MODE != 1 && c + 1 < NCHUNK) {
                v4f (*nb)[OUT_D] = wbuf[(c + 1) & 1];
#pragma unroll
                for (int p = 0; p < CP; ++p) {
                    const float4* g = &wbase[(size_t)((c + 1) * CP + p) * OUT_D + o];
                    __builtin_amdgcn_global_load_lds(
                        (const __attribute__((address_space(1))) void*)g,
                        (__attribute__((address_space(3))) void*)&nb[p][o], 16, 0, 0);
                }
            }
            v4f (*cb)[OUT_D] = wbuf[c & 1];
#pragma unroll
            for (int p = 0; p < CP; ++p) {
                v4f w, h0, h1;
                if (MODE == 1) { w.x = oc0; w.y = oc1; w.z = oc2; w.w = oc3; }
                else           { w = cb[p][o]; }
                const int k = (c * CP + p) * 2;
                if (MODE == 2) {
                    h0.x = oc0; h0.y = oc1; h0.z = oc2; h0.w = oc3;
                    h1.x = oc1; h1.y = oc2; h1.z = oc3; h1.w = oc0;
                } else {
                    h0 = *reinterpret_cast<const v4f*>(&ab[0][k]);
                    h1 = *reinterpret_cast<const v4f*>(&ab[1][k]);
                }
                if (MODE == 3) {   // keep loads alive, strip math
                    aL0 += (w.x + w.y) + (w.z + w.w);
                    aR0 += (h0.x + h0.y) + (h0.z + h0.w);
                    aL1 += (h1.x + h1.y) + (h1.z + h1.w);
                } else {
                    fz_tri(h0.x, h0.y, w.x, w.y, aL0, aR0);
                    fz_tri(h0.z, h0.w, w.z, w.w, aL0, aR0);
                    fz_tri(h1.x, h1.y, w.x, w.y, aL1, aR1);
                    fz_tri(h1.z, h1.w, w.z, w.w, aL1, aR1);
                }
            }
            if (MODE != 4) __syncthreads();
        }
    }

    if (WOUT) {
        float bl = bb[o] - fmaxf(ba[o], 0.0f);
        float br = bb[o] + fmaxf(bc[o], 0.0f);
        size_t r0 = (size_t)n0 * OUT_D + o;
        out[r0]                              = aL0 + bl;
        out[r0 + OUT_D]                      = aL1 + bl;
        out[(size_t)NN * OUT_D + r0]         = aR0 + br;
        out[(size_t)NN * OUT_D + r0 + OUT_D] = aR1 + br;
    } else {
        float s = aL0 + aR0 + aL1 + aR1;
        if (MODE == 1) s += ((volatile float*)wbuf)[tid];        // keep wbuf live
        if (MODE == 2) s += ((volatile float*)ab)[tid & 511];    // keep ab live
        sinkbuf[(size_t)blockIdx.x * 256 + tid] = s;
    }
}

#define ABL_ARGS const float* hl, const float* hr, const float4* wlr2, \
                 const float* bb, const float* ba, const float* bc,    \
                 float* out, float* sinkbuf
__global__ __launch_bounds__(256) void fzA_full(ABL_ARGS) { fz_core<0, 12, false>(hl, hr, wlr2, bb, ba, bc, out, sinkbuf); }
__global__ __launch_bounds__(256) void fzB_noW(ABL_ARGS)  { fz_core<1, 12, false>(hl, hr, wlr2, bb, ba, bc, out, sinkbuf); }
__global__ __launch_bounds__(256) void fzC_noH(ABL_ARGS)  { fz_core<2, 12, false>(hl, hr, wlr2, bb, ba, bc, out, sinkbuf); }
__global__ __launch_bounds__(256) void fzD_noV(ABL_ARGS)  { fz_core<3, 12, false>(hl, hr, wlr2, bb, ba, bc, out, sinkbuf); }
__global__ __launch_bounds__(256) void fzE_noB(ABL_ARGS)  { fz_core<4, 12, false>(hl, hr, wlr2, bb, ba, bc, out, sinkbuf); }
__global__ __launch_bounds__(256) void fz_v0(ABL_ARGS)    { fz_core<0, 1, true >(hl, hr, wlr2, bb, ba, bc, out, sinkbuf); }

// correctness-only fallback if ws too small
__global__ __launch_bounds__(256) void fz_fallback(
    const float* __restrict__ hl, const float* __restrict__ hr,
    const float* __restrict__ wb, const float* __restrict__ wa,
    const float* __restrict__ wc,
    const float* __restrict__ bb, const float* __restrict__ ba,
    const float* __restrict__ bc, float* __restrict__ out) {
    __shared__ __align__(16) v2f ab[RPB][IN_D];
    const int tid = threadIdx.x;
    const int o   = tid;
    const int n0  = blockIdx.x * RPB;
    if (tid < RPB * (IN_D / 4)) {
        int row = tid >> 6, c4 = tid & 63;
        v4f A = *reinterpret_cast<const v4f*>(&hl[(n0 + row) * IN_D + c4 * 4]);
        v4f B = *reinterpret_cast<const v4f*>(&hr[(n0 + row) * IN_D + c4 * 4]);
        v2f* dst = &ab[row][c4 * 4];
        v2f t0; t0.x = A.x; t0.y = B.x; dst[0] = t0;
        v2f t1; t1.x = A.y; t1.y = B.y; dst[1] = t1;
        v2f t2; t2.x = A.z; t2.y = B.z; dst[2] = t2;
        v2f t3; t3.x = A.w; t3.y = B.w; dst[3] = t3;
    }
    __syncthreads();
    float aL0 = 0, aR0 = 0, aL1 = 0, aR1 = 0;
    for (int i = 0; i < IN_D; ++i) {
        int wi = i * OUT_D + o;
        float wl = wb[wi] - fmaxf(wa[wi], 0.0f);
        float wr = wb[wi] + fmaxf(wc[wi], 0.0f);
        v2f h0 = ab[0][i], h1 = ab[1][i];
        fz_tri(h0.x, h0.y, wl, wr, aL0, aR0);
        fz_tri(h1.x, h1.y, wl, wr, aL1, aR1);
    }
    float bl = bb[o] - fmaxf(ba[o], 0.0f);
    float br = bb[o] + fmaxf(bc[o], 0.0f);
    size_t r0 = (size_t)n0 * OUT_D + o;
    out[r0]                              = aL0 + bl;
    out[r0 + OUT_D]                      = aL1 + bl;
    out[(size_t)NN * OUT_D + r0]         = aR0 + br;
    out[(size_t)NN * OUT_D + r0 + OUT_D] = aR1 + br;
}

extern "C" void kernel_launch(void* const* d_in, const int* in_sizes, int n_in,
                              void* d_out, int out_size, void* d_ws, size_t ws_size,
                              hipStream_t stream) {
    const float* hl = (const float*)d_in[0];
    const float* hr = (const float*)d_in[1];
    const float* wb = (const float*)d_in[2];
    const float* wa = (const float*)d_in[3];
    const float* wc = (const float*)d_in[4];
    const float* bb = (const float*)d_in[5];
    const float* ba = (const float*)d_in[6];
    const float* bc = (const float*)d_in[7];
    float* out = (float*)d_out;

    dim3 grid(NN / RPB);

    if (ws_size >= WLR_BYTES) {
        float4* wlr2 = (float4*)d_ws;
        fz_prep<<<(NPAIRS * OUT_D) / 256, 256, 0, stream>>>(wb, wa, wc, wlr2);
        if (ws_size >= ABL_BYTES) {
            float* s = (float*)((char*)d_ws + WLR_BYTES);
            fzA_full<<<grid, 256, 0, stream>>>(hl, hr, wlr2, bb, ba, bc, nullptr, s + 0 * SINK_FLOATS);
            fzB_noW <<<grid, 256, 0, stream>>>(hl, hr, wlr2, bb, ba, bc, nullptr, s + 1 * SINK_FLOATS);
            fzC_noH <<<grid, 256, 0, stream>>>(hl, hr, wlr2, bb, ba, bc, nullptr, s + 2 * SINK_FLOATS);
            fzD_noV <<<grid, 256, 0, stream>>>(hl, hr, wlr2, bb, ba, bc, nullptr, s + 3 * SINK_FLOATS);
            fzE_noB <<<grid, 256, 0, stream>>>(hl, hr, wlr2, bb, ba, bc, nullptr, s + 4 * SINK_FLOATS);
        }
        fz_v0<<<grid, 256, 0, stream>>>(hl, hr, wlr2, bb, ba, bc, out, nullptr);
    } else {
        fz_fallback<<<grid, 256, 0, stream>>>(hl, hr, wb, wa, wc, bb, ba, bc, out);
    }
}

// Round 12
// 31.908 us; speedup vs baseline: 31.7928x; 31.7928x over previous
//
#include <hip/hip_runtime.h>

#define NN     1024
#define IN_D   256
#define OUT_D  256
#define RPB    4                        // rows per block
#define KSPLIT 4                        // K-slices
#define NPAIRS (IN_D / 2)               // 128 i-pairs total
#define PPB    (NPAIRS / KSPLIT)        // 32 i-pairs per block

typedef float v2f __attribute__((ext_vector_type(2)));
typedef float v4f __attribute__((ext_vector_type(4)));

#define WLR_BYTES  (sizeof(float4) * NPAIRS * OUT_D)          // 512 KB
#define PART_BYTES (sizeof(v2f) * KSPLIT * NN * OUT_D)        // 8 MB

__global__ __launch_bounds__(256) void fz_prep(
    const float* __restrict__ wb, const float* __restrict__ wa,
    const float* __restrict__ wc, float4* __restrict__ wlr2) {
    int t = blockIdx.x * 256 + threadIdx.x;        // 0 .. NPAIRS*OUT-1
    int pr = t >> 8;
    int o  = t & (OUT_D - 1);
    int i0 = (2 * pr) * OUT_D + o;
    int i1 = i0 + OUT_D;
    float4 w;
    w.x = wb[i0] - fmaxf(wa[i0], 0.0f);            // wl(2p)
    w.y = wb[i0] + fmaxf(wc[i0], 0.0f);            // wr(2p)
    w.z = wb[i1] - fmaxf(wa[i1], 0.0f);            // wl(2p+1)
    w.w = wb[i1] + fmaxf(wc[i1], 0.0f);            // wr(2p+1)
    wlr2[t] = w;
}

__device__ __forceinline__ void fz_tri(float a, float b, float wl, float wr,
                                       v2f& acc) {
    // invariants: b >= a (hr >= hl), wr > 0
    //   min(p1..p4) = min3(a*wl, b*wl, a*wr); max(p1..p4) = max3(a*wl, b*wl, b*wr)
    float x  = a * wl;
    float y  = b * wl;
    float zl = a * wr;
    float zr = b * wr;
    v2f mm;
    mm.x = fminf(fminf(x, y), zl);                 // v_min3_f32
    mm.y = fmaxf(fmaxf(x, y), zr);                 // v_max3_f32
    acc += mm;                                     // v_pk_add_f32
}

// h = {a(2j), b(2j), a(2j+1), b(2j+1)}, w = {wl(2j), wr(2j), wl(2j+1), wr(2j+1)}
__device__ __forceinline__ void fz_pair(v4f h, v4f w, v2f& acc) {
    fz_tri(h.x, h.y, w.x, w.y, acc);
    fz_tri(h.z, h.w, w.z, w.w, acc);
}

__global__ __launch_bounds__(256) void fz_main(
    const float* __restrict__ hl, const float* __restrict__ hr,
    const float4* __restrict__ wlr2, v2f* __restrict__ part) {
    __shared__ __align__(16) v2f ab[RPB][IN_D];    // 8 KB {hl,hr} pairs

    const int tid = threadIdx.x;
    const int o   = tid;                           // this thread's o-column
    const int nb  = blockIdx.x;                    // row-block 0..255
    const int k   = blockIdx.y;                    // K-slice 0..3
    const int n0  = nb * RPB;

    // stage RPB rows of {hl,hr}: one float4-group per thread, coalesced
    {
        int row = tid >> 6;                        // 0..3
        int c4  = tid & 63;
        v4f A = *reinterpret_cast<const v4f*>(&hl[(n0 + row) * IN_D + c4 * 4]);
        v4f B = *reinterpret_cast<const v4f*>(&hr[(n0 + row) * IN_D + c4 * 4]);
        v2f* dst = &ab[row][c4 * 4];
        v2f t0; t0.x = A.x; t0.y = B.x; dst[0] = t0;
        v2f t1; t1.x = A.y; t1.y = B.y; dst[1] = t1;
        v2f t2; t2.x = A.z; t2.y = B.z; dst[2] = t2;
        v2f t3; t3.x = A.w; t3.y = B.w; dst[3] = t3;
    }
    __syncthreads();

    v2f acc0 = (v2f)(0.0f), acc1 = (v2f)(0.0f),
        acc2 = (v2f)(0.0f), acc3 = (v2f)(0.0f);

    const float4* wp   = wlr2 + (size_t)(k * PPB) * OUT_D + o;
    const int     kk0  = k * PPB * 2;

#pragma unroll 8
    for (int j = 0; j < PPB; ++j) {
        v4f w = *reinterpret_cast<const v4f*>(&wp[(size_t)j * OUT_D]);  // 16B/lane
        const int kk = kk0 + 2 * j;
        v4f h0 = *reinterpret_cast<const v4f*>(&ab[0][kk]);   // broadcast b128
        v4f h1 = *reinterpret_cast<const v4f*>(&ab[1][kk]);
        v4f h2 = *reinterpret_cast<const v4f*>(&ab[2][kk]);
        v4f h3 = *reinterpret_cast<const v4f*>(&ab[3][kk]);
        fz_pair(h0, w, acc0);
        fz_pair(h1, w, acc1);
        fz_pair(h2, w, acc2);
        fz_pair(h3, w, acc3);
    }

    // part[(k*NN + n) * OUT_D + o] as v2f {L, R}; coalesced 8B/lane
    size_t base = ((size_t)k * NN + n0) * OUT_D + o;
    part[base]              = acc0;
    part[base + OUT_D]      = acc1;
    part[base + 2 * OUT_D]  = acc2;
    part[base + 3 * OUT_D]  = acc3;
}

__global__ __launch_bounds__(256) void fz_reduce(
    const v2f* __restrict__ part,
    const float* __restrict__ bb, const float* __restrict__ ba,
    const float* __restrict__ bc, float* __restrict__ out) {
    int idx = blockIdx.x * 256 + threadIdx.x;      // 0 .. NN*OUT-1
    int o   = idx & (OUT_D - 1);
    v2f s = part[idx];
    s += part[(size_t)1 * NN * OUT_D + idx];
    s += part[(size_t)2 * NN * OUT_D + idx];
    s += part[(size_t)3 * NN * OUT_D + idx];
    float bl = bb[o] - fmaxf(ba[o], 0.0f);
    float br = bb[o] + fmaxf(bc[o], 0.0f);
    out[idx]                          = s.x + bl;
    out[(size_t)NN * OUT_D + idx]     = s.y + br;
}

// correctness-only fallback if ws too small (not expected to run)
__global__ __launch_bounds__(256) void fz_fallback(
    const float* __restrict__ hl, const float* __restrict__ hr,
    const float* __restrict__ wb, const float* __restrict__ wa,
    const float* __restrict__ wc,
    const float* __restrict__ bb, const float* __restrict__ ba,
    const float* __restrict__ bc, float* __restrict__ out) {
    __shared__ __align__(16) v2f ab[2][IN_D];
    const int tid = threadIdx.x;
    const int o   = tid;
    const int n0  = blockIdx.x * 2;
    if (tid < 2 * (IN_D / 4)) {
        int row = tid >> 6, c4 = tid & 63;
        v4f A = *reinterpret_cast<const v4f*>(&hl[(n0 + row) * IN_D + c4 * 4]);
        v4f B = *reinterpret_cast<const v4f*>(&hr[(n0 + row) * IN_D + c4 * 4]);
        v2f* dst = &ab[row][c4 * 4];
        v2f t0; t0.x = A.x; t0.y = B.x; dst[0] = t0;
        v2f t1; t1.x = A.y; t1.y = B.y; dst[1] = t1;
        v2f t2; t2.x = A.z; t2.y = B.z; dst[2] = t2;
        v2f t3; t3.x = A.w; t3.y = B.w; dst[3] = t3;
    }
    __syncthreads();
    v2f a0 = (v2f)(0.0f), a1 = (v2f)(0.0f);
    for (int i = 0; i < IN_D; ++i) {
        int wi = i * OUT_D + o;
        float wl = wb[wi] - fmaxf(wa[wi], 0.0f);
        float wr = wb[wi] + fmaxf(wc[wi], 0.0f);
        v2f h0 = ab[0][i], h1 = ab[1][i];
        fz_tri(h0.x, h0.y, wl, wr, a0);
        fz_tri(h1.x, h1.y, wl, wr, a1);
    }
    float bl = bb[o] - fmaxf(ba[o], 0.0f);
    float br = bb[o] + fmaxf(bc[o], 0.0f);
    size_t r0 = (size_t)n0 * OUT_D + o;
    out[r0]                              = a0.x + bl;
    out[r0 + OUT_D]                      = a1.x + bl;
    out[(size_t)NN * OUT_D + r0]         = a0.y + br;
    out[(size_t)NN * OUT_D + r0 + OUT_D] = a1.y + br;
}

extern "C" void kernel_launch(void* const* d_in, const int* in_sizes, int n_in,
                              void* d_out, int out_size, void* d_ws, size_t ws_size,
                              hipStream_t stream) {
    const float* hl = (const float*)d_in[0];
    const float* hr = (const float*)d_in[1];
    const float* wb = (const float*)d_in[2];
    const float* wa = (const float*)d_in[3];
    const float* wc = (const float*)d_in[4];
    const float* bb = (const float*)d_in[5];
    const float* ba = (const float*)d_in[6];
    const float* bc = (const float*)d_in[7];
    float* out = (float*)d_out;

    if (ws_size >= WLR_BYTES + PART_BYTES) {
        float4* wlr2 = (float4*)d_ws;
        v2f*    part = (v2f*)((char*)d_ws + WLR_BYTES);
        fz_prep<<<(NPAIRS * OUT_D) / 256, 256, 0, stream>>>(wb, wa, wc, wlr2);
        fz_main<<<dim3(NN / RPB, KSPLIT), 256, 0, stream>>>(hl, hr, wlr2, part);
        fz_reduce<<<(NN * OUT_D) / 256, 256, 0, stream>>>(part, bb, ba, bc, out);
    } else {
        fz_fallback<<<NN / 2, 256, 0, stream>>>(hl, hr, wb, wa, wc,
                                                bb, ba, bc, out);
    }
}

// Round 13
// 25.676 us; speedup vs baseline: 39.5085x; 1.2427x over previous
//
#include <hip/hip_runtime.h>

#define NN    1024
#define IN_D  256
#define OUT_D 256
#define RPB   2                 // rows per block -> grid = 512 = 2 blocks/CU
#define NG    4                 // K-groups per block (1024 thr = 256 o x 4 g)
#define IPG   (IN_D / NG)       // 64 i per group
#define JPP   (IPG / 2)         // 32 i-pairs per group

typedef float v2f __attribute__((ext_vector_type(2)));

__global__ __launch_bounds__(1024) void fz_one(
    const float* __restrict__ hl, const float* __restrict__ hr,
    const float* __restrict__ wb, const float* __restrict__ wa,
    const float* __restrict__ wc,
    const float* __restrict__ bb, const float* __restrict__ ba,
    const float* __restrict__ bc, float* __restrict__ out) {
    __shared__ float aS[RPB][IN_D];          // 2 KB  hl rows (SoA)
    __shared__ float bS[RPB][IN_D];          // 2 KB  hr rows
    __shared__ v2f   pl[NG][RPB][OUT_D];     // 16 KB partials {L,R}

    const int tid  = threadIdx.x;
    const int o    = tid & (OUT_D - 1);      // 0..255
    const int g    = tid >> 8;               // 0..3
    const int row0 = blockIdx.x * RPB;

    // ---- stage h rows, SoA: 1024 elements, 1 per thread, coalesced ----
    {
        int arr = tid >> 9;                  // 0 = hl, 1 = hr
        int row = (tid >> 8) & 1;
        int i   = tid & (IN_D - 1);
        float v = arr ? hr[(row0 + row) * IN_D + i]
                      : hl[(row0 + row) * IN_D + i];
        if (arr) bS[row][i] = v; else aS[row][i] = v;
    }
    __syncthreads();

    // ---- K-loop: group g owns i in [g*64, g*64+64) as 32 pairs ----
    const int i0 = g * IPG;
    // one shared voffset (elements) for all three W arrays
    int idx = i0 * OUT_D + o;

    v2f accL0 = (v2f)(0.0f), accR0 = (v2f)(0.0f);
    v2f accL1 = (v2f)(0.0f), accR1 = (v2f)(0.0f);

    // depth-1 prefetch, named scalars only
    float nb0 = wb[idx], nb1 = wb[idx + OUT_D];
    float na0 = wa[idx], na1 = wa[idx + OUT_D];
    float nc0 = wc[idx], nc1 = wc[idx + OUT_D];

#pragma unroll
    for (int jp = 0; jp < JPP; ++jp) {
        float cb0 = nb0, cb1 = nb1, ca0 = na0, ca1 = na1, cc0 = nc0, cc1 = nc1;
        if (jp + 1 < JPP) {
            idx += 2 * OUT_D;                // single voffset bump
            nb0 = wb[idx]; nb1 = wb[idx + OUT_D];
            na0 = wa[idx]; na1 = wa[idx + OUT_D];
            nc0 = wc[idx]; nc1 = wc[idx + OUT_D];
        }
        // w_l / w_r for the i-pair
        v2f WL, WR;
        WL.x = cb0 - fmaxf(ca0, 0.0f); WL.y = cb1 - fmaxf(ca1, 0.0f);
        WR.x = cb0 + fmaxf(cc0, 0.0f); WR.y = cb1 + fmaxf(cc1, 0.0f);

        const int ii = i0 + 2 * jp;
        // row 0
        {
            v2f A = *reinterpret_cast<const v2f*>(&aS[0][ii]);  // ds_read_b64 bcast
            v2f B = *reinterpret_cast<const v2f*>(&bS[0][ii]);
            v2f X = A * WL, Y = B * WL, ZL = A * WR, ZR = B * WR;
            // invariants: B>=A, WR>0 -> min4 = min3(X,Y,ZL), max4 = max3(X,Y,ZR)
            v2f mn, mx;
            mn.x = fminf(fminf(X.x, Y.x), ZL.x);   // v_min3_f32
            mn.y = fminf(fminf(X.y, Y.y), ZL.y);
            mx.x = fmaxf(fmaxf(X.x, Y.x), ZR.x);   // v_max3_f32
            mx.y = fmaxf(fmaxf(X.y, Y.y), ZR.y);
            accL0 += mn; accR0 += mx;
        }
        // row 1
        {
            v2f A = *reinterpret_cast<const v2f*>(&aS[1][ii]);
            v2f B = *reinterpret_cast<const v2f*>(&bS[1][ii]);
            v2f X = A * WL, Y = B * WL, ZL = A * WR, ZR = B * WR;
            v2f mn, mx;
            mn.x = fminf(fminf(X.x, Y.x), ZL.x);
            mn.y = fminf(fminf(X.y, Y.y), ZL.y);
            mx.x = fmaxf(fmaxf(X.x, Y.x), ZR.x);
            mx.y = fmaxf(fmaxf(X.y, Y.y), ZR.y);
            accL1 += mn; accR1 += mx;
        }
    }

    // horizontal sum over the i-pair lanes -> {L, R} per row
    {
        v2f p0; p0.x = accL0.x + accL0.y; p0.y = accR0.x + accR0.y;
        v2f p1; p1.x = accL1.x + accL1.y; p1.y = accR1.x + accR1.y;
        pl[g][0][o] = p0;
        pl[g][1][o] = p1;
    }
    __syncthreads();

    // ---- epilogue: 1024 threads = side(2) x row(2) x o(256), 1 store each ----
    {
        int side = tid >> 9;                 // 0 = out_l, 1 = out_r
        int row  = (tid >> 8) & 1;
        int oo   = tid & (OUT_D - 1);
        v2f s = pl[0][row][oo];
        s += pl[1][row][oo];
        s += pl[2][row][oo];
        s += pl[3][row][oo];
        float v = side ? s.y : s.x;
        float bias = side ? (bb[oo] + fmaxf(bc[oo], 0.0f))
                          : (bb[oo] - fmaxf(ba[oo], 0.0f));
        out[(size_t)side * NN * OUT_D + (size_t)(row0 + row) * OUT_D + oo] = v + bias;
    }
}

extern "C" void kernel_launch(void* const* d_in, const int* in_sizes, int n_in,
                              void* d_out, int out_size, void* d_ws, size_t ws_size,
                              hipStream_t stream) {
    const float* hl = (const float*)d_in[0];
    const float* hr = (const float*)d_in[1];
    const float* wb = (const float*)d_in[2];
    const float* wa = (const float*)d_in[3];
    const float* wc = (const float*)d_in[4];
    const float* bb = (const float*)d_in[5];
    const float* ba = (const float*)d_in[6];
    const float* bc = (const float*)d_in[7];
    float* out = (float*)d_out;

    fz_one<<<NN / RPB, 1024, 0, stream>>>(hl, hr, wb, wa, wc, bb, ba, bc, out);
}